// Round 1
// baseline (10635.034 us; speedup 1.0000x reference)
//
#include <hip/hip_runtime.h>

#define TT 512
#define BATCH 256
#define HH 1024

typedef _Float16 half8 __attribute__((ext_vector_type(8)));
typedef float floatx4 __attribute__((ext_vector_type(4)));

// Grid: 256 wgs (1 per CU), 256 threads (4 waves).
// wg = (bbq = wg>>4) b-block [16 batches]  x  (jb = wg&15) j-block [64 hidden].
// Wave w owns K-quarter w for the MFMAs, and j-fragment w (16 cols) for the epilogue.
// W_hh stays in VGPRs (f16 B-fragments, loaded once). h state double-buffered f16 in ws.
// Per-b-block sync: monotonic counter, release/acquire agent fences for cross-XCD visibility.
__global__ __launch_bounds__(256, 1)
void rnn_persistent(const float* __restrict__ x0,      // initial_input [256]
                    const float* __restrict__ hidden0, // [256*1024]
                    const float* __restrict__ targets, // [512*256]
                    const float* __restrict__ W_ih,    // [1024]
                    const float* __restrict__ W_hh,    // [1024*1024] row-major [j][k]
                    const float* __restrict__ b_ih,
                    const float* __restrict__ b_hh,
                    const float* __restrict__ W_out,   // [1024]
                    const float* __restrict__ b_out,   // [1]
                    float*       __restrict__ out,     // [512*256], pre-zeroed
                    _Float16*    __restrict__ hbuf0,
                    _Float16*    __restrict__ hbuf1,
                    unsigned*    __restrict__ cnt)     // [16], pre-zeroed
{
    const int wg  = blockIdx.x;
    const int jb  = wg & 15;
    const int bbq = wg >> 4;
    const int tid = threadIdx.x;
    const int w   = tid >> 6;   // wave id = K-quarter = epilogue j-frag
    const int l   = tid & 63;
    const int l15 = l & 15;
    const int lhi = l >> 4;

    __shared__ __align__(16) float x_lds[16];
    __shared__ __align__(16) float red[4][4][256];   // [src wave][jfrag][lane*4+r] 16KB
    __shared__ __align__(16) float y_red[4][16];

    // ---- one-time: preload this wave's W_hh slice as MFMA B-fragments (f16) ----
    // B frag layout (16x16x32): lane holds B[k = 8*(l>>4)+e][n = l&15], B[k][n] = W_hh[n_row][k]
    half8 wfrag[4][8];
    {
        const int kbase = w * 256 + lhi * 8;
        #pragma unroll
        for (int jf = 0; jf < 4; ++jf) {
            const float* wr = W_hh + (size_t)(jb * 64 + jf * 16 + l15) * HH + kbase;
            #pragma unroll
            for (int kk = 0; kk < 8; ++kk) {
                floatx4 lo = *(const floatx4*)(wr + kk * 32);
                floatx4 hi = *(const floatx4*)(wr + kk * 32 + 4);
                half8 f;
                f[0]=(_Float16)lo[0]; f[1]=(_Float16)lo[1]; f[2]=(_Float16)lo[2]; f[3]=(_Float16)lo[3];
                f[4]=(_Float16)hi[0]; f[5]=(_Float16)hi[1]; f[6]=(_Float16)hi[2]; f[7]=(_Float16)hi[3];
                wfrag[jf][kk] = f;
            }
        }
    }

    const int   jcol   = jb * 64 + w * 16 + l15;     // this lane's output column (epilogue)
    const float bias_l = b_ih[jcol] + b_hh[jcol];
    const float wih_l  = W_ih[jcol];
    const float wout_l = W_out[jcol];
    const float bout   = b_out[0];

    // ---- init: convert fp32 hidden -> f16 hbuf0 (this wg's 16x64 patch) ----
    {
        const int rr = tid >> 4;
        const int cc = (tid & 15) * 4;
        const float* s = hidden0 + (size_t)(bbq * 16 + rr) * HH + jb * 64 + cc;
        _Float16*    d = hbuf0   + (size_t)(bbq * 16 + rr) * HH + jb * 64 + cc;
        #pragma unroll
        for (int i = 0; i < 4; ++i) d[i] = (_Float16)s[i];
    }
    __syncthreads();                       // all stores drained (vmcnt 0) before signal
    if (tid == 0) {
        __builtin_amdgcn_fence(__ATOMIC_RELEASE, "agent");
        __hip_atomic_fetch_add(&cnt[bbq], 1u, __ATOMIC_RELAXED, __HIP_MEMORY_SCOPE_AGENT);
    }

    for (int s = 0; s < TT; ++s) {
        const _Float16* hs = (s & 1) ? hbuf1 : hbuf0;
        _Float16*       hd = (s & 1) ? hbuf0 : hbuf1;

        // ---- wait for all 16 wgs of this b-block to finish previous phase ----
        if (tid == 0) {
            const unsigned tgt = 16u * (unsigned)(s + 1);
            while (__hip_atomic_load(&cnt[bbq], __ATOMIC_RELAXED, __HIP_MEMORY_SCOPE_AGENT) < tgt)
                __builtin_amdgcn_s_sleep(8);
        }
        __syncthreads();                                   // (A)
        __builtin_amdgcn_fence(__ATOMIC_ACQUIRE, "agent"); // invalidate L1/L2 -> fresh h

        if (tid < 16)
            x_lds[tid] = (s == 0) ? x0[bbq * 16 + tid]
                                  : targets[(size_t)(s - 1) * BATCH + bbq * 16 + tid];

        // ---- A-fragments: h[16 rows x this wave's K-quarter] straight from global ----
        // A frag layout: lane holds A[m = l&15][k = 8*(l>>4)+e]
        const _Float16* hrow = hs + (size_t)(bbq * 16 + l15) * HH + w * 256 + lhi * 8;
        half8 afrag[8];
        #pragma unroll
        for (int kk = 0; kk < 8; ++kk)
            afrag[kk] = *(const half8*)(hrow + kk * 32);

        floatx4 acc[4] = {{0,0,0,0},{0,0,0,0},{0,0,0,0},{0,0,0,0}};
        #pragma unroll
        for (int kk = 0; kk < 8; ++kk) {
            #pragma unroll
            for (int jf = 0; jf < 4; ++jf)
                acc[jf] = __builtin_amdgcn_mfma_f32_16x16x32_f16(afrag[kk], wfrag[jf][kk],
                                                                 acc[jf], 0, 0, 0);
        }

        // ---- cross-wave K reduction via LDS ----
        #pragma unroll
        for (int jf = 0; jf < 4; ++jf)
            *(floatx4*)&red[w][jf][l * 4] = acc[jf];
        __syncthreads();                                   // (C)

        floatx4 pre = *(const floatx4*)&red[0][w][l * 4];
        #pragma unroll
        for (int v = 1; v < 4; ++v) {
            floatx4 t = *(const floatx4*)&red[v][w][l * 4];
            pre[0] += t[0]; pre[1] += t[1]; pre[2] += t[2]; pre[3] += t[3];
        }
        const floatx4 xv = *(const floatx4*)&x_lds[lhi * 4];

        // epilogue: lane owns D[b = lhi*4+r][jcol]
        float ht[4];
        #pragma unroll
        for (int r = 0; r < 4; ++r) {
            const float p = pre[r] + bias_l + xv[r] * wih_l;
            const float e = __expf(2.0f * p);              // tanh(p) = 1 - 2/(e^{2p}+1)
            ht[r] = 1.0f - 2.0f / (e + 1.0f);
        }

        #pragma unroll
        for (int r = 0; r < 4; ++r)
            hd[(size_t)(bbq * 16 + lhi * 4 + r) * HH + jcol] = (_Float16)ht[r];

        // ---- y partial: reduce over this wave's 16 cols, then over 4 waves ----
        float yv[4];
        #pragma unroll
        for (int r = 0; r < 4; ++r) yv[r] = ht[r] * wout_l;
        #pragma unroll
        for (int off = 1; off < 16; off <<= 1) {
            #pragma unroll
            for (int r = 0; r < 4; ++r) yv[r] += __shfl_xor(yv[r], off);
        }
        if (l15 == 0) {
            #pragma unroll
            for (int r = 0; r < 4; ++r) y_red[w][lhi * 4 + r] = yv[r];
        }
        __syncthreads();                                   // (D) also drains h' stores
        if (tid < 16) {
            const float y = y_red[0][tid] + y_red[1][tid] + y_red[2][tid] + y_red[3][tid] + bout;
            atomicAdd(&out[(size_t)s * BATCH + bbq * 16 + tid], y);
        }

        // ---- publish h' and signal ----
        if (tid == 0) {
            __builtin_amdgcn_fence(__ATOMIC_RELEASE, "agent");
            __hip_atomic_fetch_add(&cnt[bbq], 1u, __ATOMIC_RELAXED, __HIP_MEMORY_SCOPE_AGENT);
        }
    }
}

extern "C" void kernel_launch(void* const* d_in, const int* in_sizes, int n_in,
                              void* d_out, int out_size, void* d_ws, size_t ws_size,
                              hipStream_t stream)
{
    const float* x0      = (const float*)d_in[0];
    const float* hidden0 = (const float*)d_in[1];
    const float* targets = (const float*)d_in[2];
    const float* W_ih    = (const float*)d_in[3];
    const float* W_hh    = (const float*)d_in[4];
    const float* b_ih    = (const float*)d_in[5];
    const float* b_hh    = (const float*)d_in[6];
    const float* W_out   = (const float*)d_in[7];
    const float* b_out   = (const float*)d_in[8];
    float* out = (float*)d_out;

    char* ws = (char*)d_ws;
    unsigned* cnt    = (unsigned*)ws;                         // 64 B
    _Float16* hbuf0  = (_Float16*)(ws + 256);                 // 512 KB
    _Float16* hbuf1  = (_Float16*)(ws + 256 + 512 * 1024);    // 512 KB

    hipMemsetAsync(cnt, 0, 64, stream);
    hipMemsetAsync(d_out, 0, (size_t)out_size * sizeof(float), stream);

    rnn_persistent<<<256, 256, 0, stream>>>(x0, hidden0, targets, W_ih, W_hh,
                                            b_ih, b_hh, W_out, b_out,
                                            out, hbuf0, hbuf1, cnt);
}

// Round 3
// 6882.660 us; speedup vs baseline: 1.5452x; 1.5452x over previous
//
#include <hip/hip_runtime.h>

#define TT 512
#define BATCH 256
#define HH 1024

typedef _Float16 half4  __attribute__((ext_vector_type(4)));
typedef _Float16 half8  __attribute__((ext_vector_type(8)));
typedef float    floatx4 __attribute__((ext_vector_type(4)));
typedef unsigned long long u64;
typedef u64 u64x2 __attribute__((ext_vector_type(2)));

// Cross-XCD h exchange: relaxed AGENT-scope atomics (8B units). The compiler
// emits the correct gfx950 cache-bypass bits AND tracks load->use deps
// (no inline-asm loads -> no rule-18 hazard).
__device__ __forceinline__ u64 hload(const _Float16* p) {
    return __hip_atomic_load((const u64*)p, __ATOMIC_RELAXED, __HIP_MEMORY_SCOPE_AGENT);
}
__device__ __forceinline__ void hstore(_Float16* p, u64 v) {
    __hip_atomic_store((u64*)p, v, __ATOMIC_RELAXED, __HIP_MEMORY_SCOPE_AGENT);
}

// Grid: 256 wgs (1/CU), 256 threads (4 waves).
// wg = (bbq = wg>>4) batch-block [16 rows] x (jb = wg&15) j-block [64 cols].
// Wave w owns K-quarter w (MFMA) and j-fragment w (epilogue).
// W_hh lives in VGPRs as f16 B-fragments (loaded once).
// h double-buffered f16 in ws, exchanged via relaxed agent atomics.
// Sync: per-b-block monotonic counter; release = s_waitcnt vmcnt(0) + relaxed RMW.
__global__ __launch_bounds__(256, 1)
void rnn_persistent(const float* __restrict__ x0,
                    const float* __restrict__ hidden0,
                    const float* __restrict__ targets,
                    const float* __restrict__ W_ih,
                    const float* __restrict__ W_hh,
                    const float* __restrict__ b_ih,
                    const float* __restrict__ b_hh,
                    const float* __restrict__ W_out,
                    const float* __restrict__ b_out,
                    float*       __restrict__ out,     // pre-zeroed
                    _Float16*    __restrict__ hbuf0,
                    _Float16*    __restrict__ hbuf1,
                    unsigned*    __restrict__ cnt)     // [16], pre-zeroed
{
    const int wg  = blockIdx.x;
    const int jb  = wg & 15;
    const int bbq = wg >> 4;
    const int tid = threadIdx.x;
    const int w   = tid >> 6;
    const int l   = tid & 63;
    const int l15 = l & 15;
    const int lhi = l >> 4;

    __shared__ __align__(16) float    x_lds[16];
    __shared__ __align__(16) float    red[4][4][256];    // 16 KB cross-wave K reduction
    __shared__ __align__(16) float    y_red[4][16];
    __shared__ __align__(16) _Float16 hlds[16 * 64];     // 2 KB h' staging tile

    // ---- one-time: W_hh slice -> f16 MFMA B-fragments in VGPRs ----
    half8 wfrag[4][8];
    {
        const int kbase = w * 256 + lhi * 8;
        #pragma unroll
        for (int jf = 0; jf < 4; ++jf) {
            const float* wr = W_hh + (size_t)(jb * 64 + jf * 16 + l15) * HH + kbase;
            #pragma unroll
            for (int kk = 0; kk < 8; ++kk) {
                floatx4 lo = *(const floatx4*)(wr + kk * 32);
                floatx4 hi = *(const floatx4*)(wr + kk * 32 + 4);
                half8 f;
                f[0]=(_Float16)lo[0]; f[1]=(_Float16)lo[1]; f[2]=(_Float16)lo[2]; f[3]=(_Float16)lo[3];
                f[4]=(_Float16)hi[0]; f[5]=(_Float16)hi[1]; f[6]=(_Float16)hi[2]; f[7]=(_Float16)hi[3];
                wfrag[jf][kk] = f;
            }
        }
    }

    const int   jcol   = jb * 64 + w * 16 + l15;
    const float bias_l = b_ih[jcol] + b_hh[jcol];
    const float wih_l  = W_ih[jcol];
    const float wout_l = W_out[jcol];
    const float bout   = b_out[0];

    // ---- init: fp32 hidden -> f16 hbuf0 (this wg's 16x64 patch) ----
    {
        const int row = tid >> 4, cc = tid & 15;            // 256 x 8B chunks = 2 KB
        const float* s = hidden0 + (size_t)(bbq * 16 + row) * HH + jb * 64 + cc * 4;
        floatx4 f4 = *(const floatx4*)s;
        half4 h4;
        h4[0]=(_Float16)f4[0]; h4[1]=(_Float16)f4[1]; h4[2]=(_Float16)f4[2]; h4[3]=(_Float16)f4[3];
        hstore(hbuf0 + (size_t)(bbq * 16 + row) * HH + jb * 64 + cc * 4,
               __builtin_bit_cast(u64, h4));
    }
    asm volatile("s_waitcnt vmcnt(0)" ::: "memory");        // stores acked at coherence point
    __syncthreads();
    if (tid == 0)
        __hip_atomic_fetch_add(&cnt[bbq], 1u, __ATOMIC_RELAXED, __HIP_MEMORY_SCOPE_AGENT);

    for (int s = 0; s < TT; ++s) {
        const _Float16* hs = (s & 1) ? hbuf1 : hbuf0;
        _Float16*       hd = (s & 1) ? hbuf0 : hbuf1;

        // prefetch x before the wait (read-only input, plain cached load)
        float xval = 0.f;
        if (tid < 16)
            xval = (s == 0) ? x0[bbq * 16 + tid]
                            : targets[(size_t)(s - 1) * BATCH + bbq * 16 + tid];

        // ---- wait: all 16 wgs of this b-block finished previous phase ----
        if (tid == 0) {
            const unsigned tgt = 16u * (unsigned)(s + 1);
            while (__hip_atomic_load(&cnt[bbq], __ATOMIC_RELAXED,
                                     __HIP_MEMORY_SCOPE_AGENT) < tgt) {}
        }
        if (tid < 16) x_lds[tid] = xval;
        __syncthreads();                                   // (A)
        __builtin_amdgcn_sched_barrier(0);                 // keep h-loads below the poll

        // ---- A-fragments: h[16 x K-quarter] via agent-coherent loads ----
        const _Float16* hrow = hs + (size_t)(bbq * 16 + l15) * HH + w * 256 + lhi * 8;
        half8 afrag[8];
        #pragma unroll
        for (int kk = 0; kk < 8; ++kk) {
            u64x2 t;
            t[0] = hload(hrow + kk * 32);
            t[1] = hload(hrow + kk * 32 + 4);
            afrag[kk] = __builtin_bit_cast(half8, t);
        }

        floatx4 acc[4] = {{0,0,0,0},{0,0,0,0},{0,0,0,0},{0,0,0,0}};
        #pragma unroll
        for (int kk = 0; kk < 8; ++kk) {
            #pragma unroll
            for (int jf = 0; jf < 4; ++jf)
                acc[jf] = __builtin_amdgcn_mfma_f32_16x16x32_f16(afrag[kk], wfrag[jf][kk],
                                                                 acc[jf], 0, 0, 0);
        }

        // ---- cross-wave K reduction via LDS ----
        #pragma unroll
        for (int jf = 0; jf < 4; ++jf)
            *(floatx4*)&red[w][jf][l * 4] = acc[jf];
        __syncthreads();                                   // (C)

        floatx4 pre = *(const floatx4*)&red[0][w][l * 4];
        #pragma unroll
        for (int v = 1; v < 4; ++v) {
            floatx4 t = *(const floatx4*)&red[v][w][l * 4];
            pre[0] += t[0]; pre[1] += t[1]; pre[2] += t[2]; pre[3] += t[3];
        }
        const floatx4 xv = *(const floatx4*)&x_lds[lhi * 4];

        // epilogue: lane owns D[b = lhi*4+r][jcol]
        float ht[4];
        #pragma unroll
        for (int r = 0; r < 4; ++r) {
            const float p = pre[r] + bias_l + xv[r] * wih_l;
            const float e = __expf(2.0f * p);
            ht[r] = 1.0f - 2.0f / (e + 1.0f);
        }

        // stage h' in LDS (f16) for wave-0 coalesced store
        #pragma unroll
        for (int r = 0; r < 4; ++r)
            hlds[(lhi * 4 + r) * 64 + (w * 16 + l15)] = (_Float16)ht[r];

        // y partials
        float yv[4];
        #pragma unroll
        for (int r = 0; r < 4; ++r) yv[r] = ht[r] * wout_l;
        #pragma unroll
        for (int off = 1; off < 16; off <<= 1) {
            #pragma unroll
            for (int r = 0; r < 4; ++r) yv[r] += __shfl_xor(yv[r], off);
        }
        if (l15 == 0) {
            #pragma unroll
            for (int r = 0; r < 4; ++r) y_red[w][lhi * 4 + r] = yv[r];
        }
        __syncthreads();                                   // (D)

        // ---- wave 0 stores h' (4x 8B chunks/lane) and signals ----
        if (tid < 64) {
            #pragma unroll
            for (int c = 0; c < 4; ++c) {
                const int q   = tid + c * 64;              // 256 chunks = 2 KB
                const int row = q >> 4, cc = q & 15;
                u64 v = *(const u64*)&hlds[row * 64 + cc * 4];
                hstore(hd + (size_t)(bbq * 16 + row) * HH + jb * 64 + cc * 4, v);
            }
            asm volatile("s_waitcnt vmcnt(0)" ::: "memory");  // release: acked
            if (tid == 0)
                __hip_atomic_fetch_add(&cnt[bbq], 1u, __ATOMIC_RELAXED,
                                       __HIP_MEMORY_SCOPE_AGENT);
        }

        // y finalization after the signal: off the critical path
        if (tid >= 64 && tid < 80) {
            const int b = tid - 64;
            const float y = y_red[0][b] + y_red[1][b] + y_red[2][b] + y_red[3][b] + bout;
            atomicAdd(&out[(size_t)s * BATCH + bbq * 16 + b], y);
        }
    }
}

extern "C" void kernel_launch(void* const* d_in, const int* in_sizes, int n_in,
                              void* d_out, int out_size, void* d_ws, size_t ws_size,
                              hipStream_t stream)
{
    const float* x0      = (const float*)d_in[0];
    const float* hidden0 = (const float*)d_in[1];
    const float* targets = (const float*)d_in[2];
    const float* W_ih    = (const float*)d_in[3];
    const float* W_hh    = (const float*)d_in[4];
    const float* b_ih    = (const float*)d_in[5];
    const float* b_hh    = (const float*)d_in[6];
    const float* W_out   = (const float*)d_in[7];
    const float* b_out   = (const float*)d_in[8];
    float* out = (float*)d_out;

    char* ws = (char*)d_ws;
    unsigned* cnt    = (unsigned*)ws;                         // 64 B
    _Float16* hbuf0  = (_Float16*)(ws + 256);                 // 512 KB
    _Float16* hbuf1  = (_Float16*)(ws + 256 + 512 * 1024);    // 512 KB

    hipMemsetAsync(cnt, 0, 64, stream);
    hipMemsetAsync(d_out, 0, (size_t)out_size * sizeof(float), stream);

    rnn_persistent<<<256, 256, 0, stream>>>(x0, hidden0, targets, W_ih, W_hh,
                                            b_ih, b_hh, W_out, b_out,
                                            out, hbuf0, hbuf1, cnt);
}

// Round 4
// 4111.991 us; speedup vs baseline: 2.5863x; 1.6738x over previous
//
#include <hip/hip_runtime.h>

#define TT 512
#define BATCH 256
#define HH 1024

typedef _Float16 half4  __attribute__((ext_vector_type(4)));
typedef _Float16 half8  __attribute__((ext_vector_type(8)));
typedef float    floatx4 __attribute__((ext_vector_type(4)));
typedef unsigned long long u64;
typedef u64 u64x2 __attribute__((ext_vector_type(2)));

// Cross-XCD h exchange: relaxed AGENT-scope atomics (8B units). Compiler emits
// gfx950 cache-bypass bits AND tracks load->use deps (no rule-18 hazard).
__device__ __forceinline__ u64 hload(const _Float16* p) {
    return __hip_atomic_load((const u64*)p, __ATOMIC_RELAXED, __HIP_MEMORY_SCOPE_AGENT);
}
__device__ __forceinline__ void hstore(_Float16* p, u64 v) {
    __hip_atomic_store((u64*)p, v, __ATOMIC_RELAXED, __HIP_MEMORY_SCOPE_AGENT);
}

// Grid: 128 wgs, 256 threads (4 waves).
// wg = (bbq = wg>>3) batch-block [16 rows] x (jb = wg&7) j-block [128 cols].
// Wave w owns K-quarter w (MFMA); epilogue: wave w owns j-frags {w, w+4}.
// W_hh f16 in VGPRs: 128 cols x 1024 K = 256 VGPR/lane (dup 16 -> 8: halves
// the per-step uncached h traffic, the R3 limiter).
// Sync: per-b-group counter; release = s_waitcnt vmcnt(0) + relaxed RMW.
__global__ __launch_bounds__(256, 1)
void rnn_persistent(const float* __restrict__ x0,
                    const float* __restrict__ hidden0,
                    const float* __restrict__ targets,
                    const float* __restrict__ W_ih,
                    const float* __restrict__ W_hh,
                    const float* __restrict__ b_ih,
                    const float* __restrict__ b_hh,
                    const float* __restrict__ W_out,
                    const float* __restrict__ b_out,
                    float*       __restrict__ out,     // pre-zeroed
                    _Float16*    __restrict__ hbuf0,
                    _Float16*    __restrict__ hbuf1,
                    unsigned*    __restrict__ cnt)     // [16], pre-zeroed
{
    const int wg  = blockIdx.x;
    const int jb  = wg & 7;
    const int bbq = wg >> 3;
    const int tid = threadIdx.x;
    const int w   = tid >> 6;
    const int l   = tid & 63;
    const int l15 = l & 15;
    const int lhi = l >> 4;

    __shared__ __align__(16) float    x_lds[16];
    __shared__ __align__(16) float    red[4][8][256];    // 32 KB cross-wave K reduction
    __shared__ __align__(16) float    y_red[4][16];
    __shared__ __align__(16) _Float16 hlds[16 * 128];    // 4 KB h' staging tile

    // ---- one-time: W_hh slice (128 cols x 1024 K) -> f16 B-frags in VGPRs ----
    half8 wfrag[8][8];
    {
        const int kbase = w * 256 + lhi * 8;
        #pragma unroll
        for (int jf = 0; jf < 8; ++jf) {
            const float* wr = W_hh + (size_t)(jb * 128 + jf * 16 + l15) * HH + kbase;
            #pragma unroll
            for (int kk = 0; kk < 8; ++kk) {
                floatx4 lo = *(const floatx4*)(wr + kk * 32);
                floatx4 hi = *(const floatx4*)(wr + kk * 32 + 4);
                half8 f;
                f[0]=(_Float16)lo[0]; f[1]=(_Float16)lo[1]; f[2]=(_Float16)lo[2]; f[3]=(_Float16)lo[3];
                f[4]=(_Float16)hi[0]; f[5]=(_Float16)hi[1]; f[6]=(_Float16)hi[2]; f[7]=(_Float16)hi[3];
                wfrag[jf][kk] = f;
            }
        }
    }

    const int   jcol0  = jb * 128 + w * 16 + l15;        // epilogue col (jf = w)
    const int   jcol1  = jcol0 + 64;                     // epilogue col (jf = w+4)
    const float bias0  = b_ih[jcol0] + b_hh[jcol0];
    const float bias1  = b_ih[jcol1] + b_hh[jcol1];
    const float wih0   = W_ih[jcol0], wih1 = W_ih[jcol1];
    const float wout0  = W_out[jcol0], wout1 = W_out[jcol1];
    const float bout   = (jb == 0) ? b_out[0] : 0.f;     // add b_out exactly once

    // ---- init: fp32 hidden -> f16 hbuf0 (this wg's 16 rows x 128-col slice) ----
    #pragma unroll
    for (int c = 0; c < 2; ++c) {
        const int q   = tid + c * 256;                   // 512 x 8B chunks = 4 KB
        const int row = q >> 5, cc = q & 31;
        const float* s = hidden0 + (size_t)(bbq * 16 + row) * HH + jb * 128 + cc * 4;
        floatx4 f4 = *(const floatx4*)s;
        half4 h4;
        h4[0]=(_Float16)f4[0]; h4[1]=(_Float16)f4[1]; h4[2]=(_Float16)f4[2]; h4[3]=(_Float16)f4[3];
        hstore(hbuf0 + (size_t)(bbq * 16 + row) * HH + jb * 128 + cc * 4,
               __builtin_bit_cast(u64, h4));
    }
    asm volatile("s_waitcnt vmcnt(0)" ::: "memory");     // stores acked at coherence point
    __syncthreads();
    if (tid == 0)
        __hip_atomic_fetch_add(&cnt[bbq], 1u, __ATOMIC_RELAXED, __HIP_MEMORY_SCOPE_AGENT);

    for (int s = 0; s < TT; ++s) {
        const _Float16* hs = (s & 1) ? hbuf1 : hbuf0;
        _Float16*       hd = (s & 1) ? hbuf0 : hbuf1;

        // prefetch x before the wait (read-only input, plain cached load)
        float xval = 0.f;
        if (tid < 16)
            xval = (s == 0) ? x0[bbq * 16 + tid]
                            : targets[(size_t)(s - 1) * BATCH + bbq * 16 + tid];

        // ---- wait: all 8 wgs of this b-group finished previous phase ----
        if (tid == 0) {
            const unsigned tgt = 8u * (unsigned)(s + 1);
            while (__hip_atomic_load(&cnt[bbq], __ATOMIC_RELAXED,
                                     __HIP_MEMORY_SCOPE_AGENT) < tgt) {}
        }
        if (tid < 16) x_lds[tid] = xval;
        __syncthreads();                                   // (A)
        __builtin_amdgcn_sched_barrier(0);                 // keep h-loads below the poll

        // ---- A-fragments: h[16 x K-quarter] via agent-coherent loads ----
        const _Float16* hrow = hs + (size_t)(bbq * 16 + l15) * HH + w * 256 + lhi * 8;
        half8 afrag[8];
        #pragma unroll
        for (int kk = 0; kk < 8; ++kk) {
            u64x2 t;
            t[0] = hload(hrow + kk * 32);
            t[1] = hload(hrow + kk * 32 + 4);
            afrag[kk] = __builtin_bit_cast(half8, t);
        }

        floatx4 acc[8] = {{0,0,0,0},{0,0,0,0},{0,0,0,0},{0,0,0,0},
                          {0,0,0,0},{0,0,0,0},{0,0,0,0},{0,0,0,0}};
        #pragma unroll
        for (int kk = 0; kk < 8; ++kk) {
            #pragma unroll
            for (int jf = 0; jf < 8; ++jf)
                acc[jf] = __builtin_amdgcn_mfma_f32_16x16x32_f16(afrag[kk], wfrag[jf][kk],
                                                                 acc[jf], 0, 0, 0);
        }

        // ---- cross-wave K reduction via LDS ----
        #pragma unroll
        for (int jf = 0; jf < 8; ++jf)
            *(floatx4*)&red[w][jf][l * 4] = acc[jf];
        __syncthreads();                                   // (C)

        floatx4 pre0 = *(const floatx4*)&red[0][w][l * 4];
        floatx4 pre1 = *(const floatx4*)&red[0][w + 4][l * 4];
        #pragma unroll
        for (int v = 1; v < 4; ++v) {
            floatx4 t0 = *(const floatx4*)&red[v][w][l * 4];
            floatx4 t1 = *(const floatx4*)&red[v][w + 4][l * 4];
            pre0[0] += t0[0]; pre0[1] += t0[1]; pre0[2] += t0[2]; pre0[3] += t0[3];
            pre1[0] += t1[0]; pre1[1] += t1[1]; pre1[2] += t1[2]; pre1[3] += t1[3];
        }
        const floatx4 xv = *(const floatx4*)&x_lds[lhi * 4];

        // epilogue: lane owns D[b = lhi*4+r][jcol0] and [jcol1]
        float ht0[4], ht1[4];
        #pragma unroll
        for (int r = 0; r < 4; ++r) {
            const float p0 = pre0[r] + bias0 + xv[r] * wih0;
            const float p1 = pre1[r] + bias1 + xv[r] * wih1;
            const float e0 = __expf(2.0f * p0);
            const float e1 = __expf(2.0f * p1);
            ht0[r] = 1.0f - 2.0f / (e0 + 1.0f);
            ht1[r] = 1.0f - 2.0f / (e1 + 1.0f);
        }

        // stage h' in LDS (f16) for wave-0 coalesced store
        #pragma unroll
        for (int r = 0; r < 4; ++r) {
            hlds[(lhi * 4 + r) * 128 + (w * 16 + l15)]      = (_Float16)ht0[r];
            hlds[(lhi * 4 + r) * 128 + (w * 16 + l15) + 64] = (_Float16)ht1[r];
        }

        // y partials over this lane's 2 cols, reduce over 16 lanes -> 32 cols/wave
        float yv[4];
        #pragma unroll
        for (int r = 0; r < 4; ++r) yv[r] = ht0[r] * wout0 + ht1[r] * wout1;
        #pragma unroll
        for (int off = 1; off < 16; off <<= 1) {
            #pragma unroll
            for (int r = 0; r < 4; ++r) yv[r] += __shfl_xor(yv[r], off);
        }
        if (l15 == 0) {
            #pragma unroll
            for (int r = 0; r < 4; ++r) y_red[w][lhi * 4 + r] = yv[r];
        }
        __syncthreads();                                   // (D)

        // ---- wave 0 stores h' (8x 8B chunks/lane = 4 KB) and signals ----
        if (tid < 64) {
            #pragma unroll
            for (int c = 0; c < 8; ++c) {
                const int q   = tid + c * 64;              // 512 chunks
                const int row = q >> 5, cc = q & 31;
                u64 v = *(const u64*)&hlds[row * 128 + cc * 4];
                hstore(hd + (size_t)(bbq * 16 + row) * HH + jb * 128 + cc * 4, v);
            }
            asm volatile("s_waitcnt vmcnt(0)" ::: "memory");  // release: acked
            if (tid == 0)
                __hip_atomic_fetch_add(&cnt[bbq], 1u, __ATOMIC_RELAXED,
                                       __HIP_MEMORY_SCOPE_AGENT);
        }

        // y finalization after the signal: off the critical path
        if (tid >= 64 && tid < 80) {
            const int b = tid - 64;
            const float y = y_red[0][b] + y_red[1][b] + y_red[2][b] + y_red[3][b] + bout;
            atomicAdd(&out[(size_t)s * BATCH + bbq * 16 + b], y);
        }
    }
}

extern "C" void kernel_launch(void* const* d_in, const int* in_sizes, int n_in,
                              void* d_out, int out_size, void* d_ws, size_t ws_size,
                              hipStream_t stream)
{
    const float* x0      = (const float*)d_in[0];
    const float* hidden0 = (const float*)d_in[1];
    const float* targets = (const float*)d_in[2];
    const float* W_ih    = (const float*)d_in[3];
    const float* W_hh    = (const float*)d_in[4];
    const float* b_ih    = (const float*)d_in[5];
    const float* b_hh    = (const float*)d_in[6];
    const float* W_out   = (const float*)d_in[7];
    const float* b_out   = (const float*)d_in[8];
    float* out = (float*)d_out;

    char* ws = (char*)d_ws;
    unsigned* cnt    = (unsigned*)ws;                         // 64 B
    _Float16* hbuf0  = (_Float16*)(ws + 256);                 // 512 KB
    _Float16* hbuf1  = (_Float16*)(ws + 256 + 512 * 1024);    // 512 KB

    hipMemsetAsync(cnt, 0, 64, stream);
    hipMemsetAsync(d_out, 0, (size_t)out_size * sizeof(float), stream);

    rnn_persistent<<<128, 256, 0, stream>>>(x0, hidden0, targets, W_ih, W_hh,
                                            b_ih, b_hh, W_out, b_out,
                                            out, hbuf0, hbuf1, cnt);
}

// Round 5
// 3603.164 us; speedup vs baseline: 2.9516x; 1.1412x over previous
//
#include <hip/hip_runtime.h>

#define TT 512
#define BATCH 256
#define HH 1024

typedef _Float16 half4  __attribute__((ext_vector_type(4)));
typedef _Float16 half8  __attribute__((ext_vector_type(8)));
typedef float    floatx4 __attribute__((ext_vector_type(4)));
typedef unsigned long long u64;

// Cross-XCD h exchange: relaxed AGENT-scope atomics (8B). Compiler emits the
// gfx950 cache-bypass bits AND tracks load->use deps (no rule-18 hazard).
__device__ __forceinline__ u64 hload(const _Float16* p) {
    return __hip_atomic_load((const u64*)p, __ATOMIC_RELAXED, __HIP_MEMORY_SCOPE_AGENT);
}
__device__ __forceinline__ void hstore(_Float16* p, u64 v) {
    __hip_atomic_store((u64*)p, v, __ATOMIC_RELAXED, __HIP_MEMORY_SCOPE_AGENT);
}

// Grid: 128 wgs, 256 threads (4 waves).
// wg = (bbq = wg>>3) batch-block [16 rows] x (jb = wg&7) j-block [128 cols].
// W_hh f16 in VGPRs (128 cols x 1024 K). h exchanged via agent atomics, but
// now COALESCED: whole 16x1024 h-tile staged to LDS (row-consecutive 8B
// loads -> 64B-line efficient), MFMA A-frags read from LDS (XOR-swizzled).
__global__ __launch_bounds__(256, 1)
void rnn_persistent(const float* __restrict__ x0,
                    const float* __restrict__ hidden0,
                    const float* __restrict__ targets,
                    const float* __restrict__ W_ih,
                    const float* __restrict__ W_hh,
                    const float* __restrict__ b_ih,
                    const float* __restrict__ b_hh,
                    const float* __restrict__ W_out,
                    const float* __restrict__ b_out,
                    float*       __restrict__ out,     // pre-zeroed
                    _Float16*    __restrict__ hbuf0,
                    _Float16*    __restrict__ hbuf1,
                    unsigned*    __restrict__ cnt)     // [16], pre-zeroed
{
    const int wg  = blockIdx.x;
    const int jb  = wg & 7;
    const int bbq = wg >> 3;
    const int tid = threadIdx.x;
    const int w   = tid >> 6;
    const int l   = tid & 63;
    const int l15 = l & 15;
    const int lhi = l >> 4;

    __shared__ __align__(16) float    x_lds[16];
    __shared__ __align__(16) float    red[4][8][256];    // 32 KB cross-wave K reduction
    __shared__ __align__(16) float    y_red[4][16];
    __shared__ __align__(16) _Float16 hlds[16 * 128];    // 4 KB h' staging tile
    __shared__ __align__(16) _Float16 hstage[16 * 1024]; // 32 KB h-tile stage (swizzled)

    // ---- one-time: W_hh slice (128 cols x 1024 K) -> f16 B-frags in VGPRs ----
    half8 wfrag[8][8];
    {
        const int kbase = w * 256 + lhi * 8;
        #pragma unroll
        for (int jf = 0; jf < 8; ++jf) {
            const float* wr = W_hh + (size_t)(jb * 128 + jf * 16 + l15) * HH + kbase;
            #pragma unroll
            for (int kk = 0; kk < 8; ++kk) {
                floatx4 lo = *(const floatx4*)(wr + kk * 32);
                floatx4 hi = *(const floatx4*)(wr + kk * 32 + 4);
                half8 f;
                f[0]=(_Float16)lo[0]; f[1]=(_Float16)lo[1]; f[2]=(_Float16)lo[2]; f[3]=(_Float16)lo[3];
                f[4]=(_Float16)hi[0]; f[5]=(_Float16)hi[1]; f[6]=(_Float16)hi[2]; f[7]=(_Float16)hi[3];
                wfrag[jf][kk] = f;
            }
        }
    }

    const int   jcol0  = jb * 128 + w * 16 + l15;
    const int   jcol1  = jcol0 + 64;
    const float bias0  = b_ih[jcol0] + b_hh[jcol0];
    const float bias1  = b_ih[jcol1] + b_hh[jcol1];
    const float wih0   = W_ih[jcol0], wih1 = W_ih[jcol1];
    const float wout0  = W_out[jcol0], wout1 = W_out[jcol1];
    const float bout   = (jb == 0) ? b_out[0] : 0.f;

    // precomputed swizzled LDS byte-addrs for the 8 A-frag ds_read_b128
    int lra[8];
    #pragma unroll
    for (int kk = 0; kk < 8; ++kk) {
        const int cb = w * 512 + lhi * 16 + kk * 64;     // logical col byte
        lra[kk] = l15 * 2048 + (cb ^ ((l15 & 7) << 4));
    }
    char* hstage_b = (char*)hstage;

    // ---- init: fp32 hidden -> f16 hbuf0 (this wg's 16 rows x 128-col slice) ----
    #pragma unroll
    for (int c = 0; c < 2; ++c) {
        const int q   = tid + c * 256;
        const int row = q >> 5, cc = q & 31;
        const float* s = hidden0 + (size_t)(bbq * 16 + row) * HH + jb * 128 + cc * 4;
        floatx4 f4 = *(const floatx4*)s;
        half4 h4;
        h4[0]=(_Float16)f4[0]; h4[1]=(_Float16)f4[1]; h4[2]=(_Float16)f4[2]; h4[3]=(_Float16)f4[3];
        hstore(hbuf0 + (size_t)(bbq * 16 + row) * HH + jb * 128 + cc * 4,
               __builtin_bit_cast(u64, h4));
    }
    asm volatile("s_waitcnt vmcnt(0)" ::: "memory");
    __syncthreads();
    if (tid == 0)
        __hip_atomic_fetch_add(&cnt[bbq], 1u, __ATOMIC_RELAXED, __HIP_MEMORY_SCOPE_AGENT);

    for (int s = 0; s < TT; ++s) {
        const _Float16* hs = (s & 1) ? hbuf1 : hbuf0;
        _Float16*       hd = (s & 1) ? hbuf0 : hbuf1;

        float xval = 0.f;
        if (tid < 16)
            xval = (s == 0) ? x0[bbq * 16 + tid]
                            : targets[(size_t)(s - 1) * BATCH + bbq * 16 + tid];

        if (tid == 0) {
            const unsigned tgt = 8u * (unsigned)(s + 1);
            while (__hip_atomic_load(&cnt[bbq], __ATOMIC_RELAXED,
                                     __HIP_MEMORY_SCOPE_AGENT) < tgt) {}
        }
        if (tid < 16) x_lds[tid] = xval;
        __syncthreads();                                   // (A)
        __builtin_amdgcn_sched_barrier(0);

        // ---- coalesced stage: 16 row-consecutive 8B loads -> swizzled LDS ----
        {
            const _Float16* sb = hs + (size_t)bbq * 16 * HH;
            u64 sv[16];
            #pragma unroll
            for (int r = 0; r < 16; ++r)
                sv[r] = hload(sb + r * HH + tid * 4);      // byte: r*2048 + tid*8
            __builtin_amdgcn_sched_barrier(0);             // all loads issue first
            #pragma unroll
            for (int r = 0; r < 16; ++r)
                *(u64*)(hstage_b + r * 2048 + ((tid * 8) ^ ((r & 7) << 4))) = sv[r];
        }
        __syncthreads();                                   // (B)

        // ---- A-fragments from LDS (swizzled, conflict-free-ish b128) ----
        half8 afrag[8];
        #pragma unroll
        for (int kk = 0; kk < 8; ++kk)
            afrag[kk] = *(const half8*)(hstage_b + lra[kk]);

        floatx4 acc[8] = {{0,0,0,0},{0,0,0,0},{0,0,0,0},{0,0,0,0},
                          {0,0,0,0},{0,0,0,0},{0,0,0,0},{0,0,0,0}};
        #pragma unroll
        for (int kk = 0; kk < 8; ++kk) {
            #pragma unroll
            for (int jf = 0; jf < 8; ++jf)
                acc[jf] = __builtin_amdgcn_mfma_f32_16x16x32_f16(afrag[kk], wfrag[jf][kk],
                                                                 acc[jf], 0, 0, 0);
        }

        // ---- cross-wave K reduction via LDS ----
        #pragma unroll
        for (int jf = 0; jf < 8; ++jf)
            *(floatx4*)&red[w][jf][l * 4] = acc[jf];
        __syncthreads();                                   // (C)

        floatx4 pre0 = *(const floatx4*)&red[0][w][l * 4];
        floatx4 pre1 = *(const floatx4*)&red[0][w + 4][l * 4];
        #pragma unroll
        for (int v = 1; v < 4; ++v) {
            floatx4 t0 = *(const floatx4*)&red[v][w][l * 4];
            floatx4 t1 = *(const floatx4*)&red[v][w + 4][l * 4];
            pre0[0] += t0[0]; pre0[1] += t0[1]; pre0[2] += t0[2]; pre0[3] += t0[3];
            pre1[0] += t1[0]; pre1[1] += t1[1]; pre1[2] += t1[2]; pre1[3] += t1[3];
        }
        const floatx4 xv = *(const floatx4*)&x_lds[lhi * 4];

        float ht0[4], ht1[4];
        #pragma unroll
        for (int r = 0; r < 4; ++r) {
            const float p0 = pre0[r] + bias0 + xv[r] * wih0;
            const float p1 = pre1[r] + bias1 + xv[r] * wih1;
            const float e0 = __expf(2.0f * p0);
            const float e1 = __expf(2.0f * p1);
            ht0[r] = 1.0f - 2.0f / (e0 + 1.0f);
            ht1[r] = 1.0f - 2.0f / (e1 + 1.0f);
        }

        #pragma unroll
        for (int r = 0; r < 4; ++r) {
            hlds[(lhi * 4 + r) * 128 + (w * 16 + l15)]      = (_Float16)ht0[r];
            hlds[(lhi * 4 + r) * 128 + (w * 16 + l15) + 64] = (_Float16)ht1[r];
        }

        float yv[4];
        #pragma unroll
        for (int r = 0; r < 4; ++r) yv[r] = ht0[r] * wout0 + ht1[r] * wout1;
        #pragma unroll
        for (int off = 1; off < 16; off <<= 1) {
            #pragma unroll
            for (int r = 0; r < 4; ++r) yv[r] += __shfl_xor(yv[r], off);
        }
        if (l15 == 0) {
            #pragma unroll
            for (int r = 0; r < 4; ++r) y_red[w][lhi * 4 + r] = yv[r];
        }
        __syncthreads();                                   // (D)

        // ---- wave 0 stores h' (8x coalesced 8B chunks/lane) and signals ----
        if (tid < 64) {
            #pragma unroll
            for (int c = 0; c < 8; ++c) {
                const int q   = tid + c * 64;
                const int row = q >> 5, cc = q & 31;
                u64 v = *(const u64*)&hlds[row * 128 + cc * 4];
                hstore(hd + (size_t)(bbq * 16 + row) * HH + jb * 128 + cc * 4, v);
            }
            asm volatile("s_waitcnt vmcnt(0)" ::: "memory");
            if (tid == 0)
                __hip_atomic_fetch_add(&cnt[bbq], 1u, __ATOMIC_RELAXED,
                                       __HIP_MEMORY_SCOPE_AGENT);
        }

        if (tid >= 64 && tid < 80) {
            const int b = tid - 64;
            const float y = y_red[0][b] + y_red[1][b] + y_red[2][b] + y_red[3][b] + bout;
            atomicAdd(&out[(size_t)s * BATCH + bbq * 16 + b], y);
        }
    }
}

extern "C" void kernel_launch(void* const* d_in, const int* in_sizes, int n_in,
                              void* d_out, int out_size, void* d_ws, size_t ws_size,
                              hipStream_t stream)
{
    const float* x0      = (const float*)d_in[0];
    const float* hidden0 = (const float*)d_in[1];
    const float* targets = (const float*)d_in[2];
    const float* W_ih    = (const float*)d_in[3];
    const float* W_hh    = (const float*)d_in[4];
    const float* b_ih    = (const float*)d_in[5];
    const float* b_hh    = (const float*)d_in[6];
    const float* W_out   = (const float*)d_in[7];
    const float* b_out   = (const float*)d_in[8];
    float* out = (float*)d_out;

    char* ws = (char*)d_ws;
    unsigned* cnt    = (unsigned*)ws;                         // 64 B
    _Float16* hbuf0  = (_Float16*)(ws + 256);                 // 512 KB
    _Float16* hbuf1  = (_Float16*)(ws + 256 + 512 * 1024);    // 512 KB

    hipMemsetAsync(cnt, 0, 64, stream);
    hipMemsetAsync(d_out, 0, (size_t)out_size * sizeof(float), stream);

    rnn_persistent<<<128, 256, 0, stream>>>(x0, hidden0, targets, W_ih, W_hh,
                                            b_ih, b_hh, W_out, b_out,
                                            out, hbuf0, hbuf1, cnt);
}

// Round 7
// 2434.539 us; speedup vs baseline: 4.3684x; 1.4800x over previous
//
#include <hip/hip_runtime.h>

#define TT 512
#define BATCH 256
#define HH 1024

typedef _Float16 half4  __attribute__((ext_vector_type(4)));
typedef _Float16 half8  __attribute__((ext_vector_type(8)));
typedef float    floatx4 __attribute__((ext_vector_type(4)));
typedef unsigned long long u64;
typedef u64 u64x2 __attribute__((ext_vector_type(2)));

// Agent-scope (MALL-coherent) 8B ops — correctness fallback path + init.
__device__ __forceinline__ u64 hload(const _Float16* p) {
    return __hip_atomic_load((const u64*)p, __ATOMIC_RELAXED, __HIP_MEMORY_SCOPE_AGENT);
}
__device__ __forceinline__ void hstore(_Float16* p, u64 v) {
    __hip_atomic_store((u64*)p, v, __ATOMIC_RELAXED, __HIP_MEMORY_SCOPE_AGENT);
}

// One RNN step-loop. FAST = all 8 wgs of this b-group verified on ONE XCD:
// h exchange via volatile (L2-served) 16B ops + L2-point counter.
// !FAST = agent-scope 8B atomics via MALL (placement-agnostic, R5 path).
template<bool FAST>
__device__ __forceinline__ void run_steps(
    int bbq, int jb, int tid, int w, int l15, int lhi,
    const float* __restrict__ x0, const float* __restrict__ targets,
    float* __restrict__ out,
    _Float16* __restrict__ hbuf0, _Float16* __restrict__ hbuf1,
    unsigned* __restrict__ cnt, unsigned* __restrict__ cnt2,
    const half8 (&wfrag)[8][8], const int (&lra)[8],
    float bias0, float bias1, float wih0, float wih1,
    float wout0, float wout1, float bout,
    float* x_lds, float* red, float* y_red,
    _Float16* hlds, char* hstage_b)
{
    const int l = lhi * 16 + l15;                          // lane id (tid & 63)

    for (int s = 0; s < TT; ++s) {
        const _Float16* hs = (s & 1) ? hbuf1 : hbuf0;
        _Float16*       hd = (s & 1) ? hbuf0 : hbuf1;

        float xval = 0.f;
        if (tid < 16)
            xval = (s == 0) ? x0[bbq * 16 + tid]
                            : targets[(size_t)(s - 1) * BATCH + bbq * 16 + tid];

        if (tid == 0) {
            if (FAST) {
                const unsigned tgt = 8u * (unsigned)s;       // prev steps complete
                while (*(volatile const unsigned*)&cnt2[bbq] < tgt) {}
            } else {
                const unsigned tgt = 8u * (unsigned)(s + 1); // init + prev steps
                while (__hip_atomic_load(&cnt[bbq], __ATOMIC_RELAXED,
                                         __HIP_MEMORY_SCOPE_AGENT) < tgt) {}
            }
        }
        if (tid < 16) x_lds[tid] = xval;
        __syncthreads();                                   // (A)
        __builtin_amdgcn_sched_barrier(0);

        // ---- stage group h-tile (16 x 1024 f16 = 32 KB) into swizzled LDS ----
        if (FAST) {
            const char* gsrc = (const char*)(hs + (size_t)bbq * 16 * HH);
            u64x2 sv[8];
            #pragma unroll
            for (int i = 0; i < 8; ++i) {
                const int c = tid + i * 256;               // 2048 x 16B chunks
                sv[i] = *(volatile const u64x2*)(gsrc + (c >> 7) * 2048 + (c & 127) * 16);
            }
            __builtin_amdgcn_sched_barrier(0);             // all loads issue first
            #pragma unroll
            for (int i = 0; i < 8; ++i) {
                const int c = tid + i * 256;
                const int row = c >> 7, colb = (c & 127) * 16;
                *(u64x2*)(hstage_b + row * 2048 + (colb ^ ((row & 7) << 4))) = sv[i];
            }
        } else {
            const _Float16* sb = hs + (size_t)bbq * 16 * HH;
            u64 sv[16];
            #pragma unroll
            for (int r = 0; r < 16; ++r)
                sv[r] = hload(sb + r * HH + tid * 4);
            __builtin_amdgcn_sched_barrier(0);
            #pragma unroll
            for (int r = 0; r < 16; ++r)
                *(u64*)(hstage_b + r * 2048 + ((tid * 8) ^ ((r & 7) << 4))) = sv[r];
        }
        __syncthreads();                                   // (B)

        // ---- A-fragments from LDS (swizzled b128 reads) ----
        half8 afrag[8];
        #pragma unroll
        for (int kk = 0; kk < 8; ++kk)
            afrag[kk] = *(const half8*)(hstage_b + lra[kk]);

        floatx4 acc[8] = {{0,0,0,0},{0,0,0,0},{0,0,0,0},{0,0,0,0},
                          {0,0,0,0},{0,0,0,0},{0,0,0,0},{0,0,0,0}};
        #pragma unroll
        for (int kk = 0; kk < 8; ++kk) {
            #pragma unroll
            for (int jf = 0; jf < 8; ++jf)
                acc[jf] = __builtin_amdgcn_mfma_f32_16x16x32_f16(afrag[kk], wfrag[jf][kk],
                                                                 acc[jf], 0, 0, 0);
        }

        // ---- cross-wave K reduction via LDS ----
        #pragma unroll
        for (int jf = 0; jf < 8; ++jf)
            *(floatx4*)&red[(w * 8 + jf) * 256 + l * 4] = acc[jf];   // FIXED index
        __syncthreads();                                   // (C)

        floatx4 pre0 = *(const floatx4*)&red[(0 * 8 + w) * 256 + l * 4];
        floatx4 pre1 = *(const floatx4*)&red[(0 * 8 + w + 4) * 256 + l * 4];
        #pragma unroll
        for (int v = 1; v < 4; ++v) {
            floatx4 t0 = *(const floatx4*)&red[(v * 8 + w) * 256 + l * 4];
            floatx4 t1 = *(const floatx4*)&red[(v * 8 + w + 4) * 256 + l * 4];
            pre0[0] += t0[0]; pre0[1] += t0[1]; pre0[2] += t0[2]; pre0[3] += t0[3];
            pre1[0] += t1[0]; pre1[1] += t1[1]; pre1[2] += t1[2]; pre1[3] += t1[3];
        }
        const floatx4 xv = *(const floatx4*)&x_lds[lhi * 4];

        float ht0[4], ht1[4];
        #pragma unroll
        for (int r = 0; r < 4; ++r) {
            const float p0 = pre0[r] + bias0 + xv[r] * wih0;
            const float p1 = pre1[r] + bias1 + xv[r] * wih1;
            const float e0 = __expf(2.0f * p0);
            const float e1 = __expf(2.0f * p1);
            ht0[r] = 1.0f - 2.0f / (e0 + 1.0f);
            ht1[r] = 1.0f - 2.0f / (e1 + 1.0f);
        }

        #pragma unroll
        for (int r = 0; r < 4; ++r) {
            hlds[(lhi * 4 + r) * 128 + (w * 16 + l15)]      = (_Float16)ht0[r];
            hlds[(lhi * 4 + r) * 128 + (w * 16 + l15) + 64] = (_Float16)ht1[r];
        }

        float yv[4];
        #pragma unroll
        for (int r = 0; r < 4; ++r) yv[r] = ht0[r] * wout0 + ht1[r] * wout1;
        #pragma unroll
        for (int off = 1; off < 16; off <<= 1) {
            #pragma unroll
            for (int r = 0; r < 4; ++r) yv[r] += __shfl_xor(yv[r], off);
        }
        if (l15 == 0) {
            #pragma unroll
            for (int r = 0; r < 4; ++r) y_red[w * 16 + lhi * 4 + r] = yv[r];
        }
        __syncthreads();                                   // (D)

        // ---- publish h' and signal ----
        if (FAST) {
            {   // all 256 threads: one 16B volatile (L2) store each
                const int row = tid >> 4, ch = tid & 15;
                u64x2 v = *(const u64x2*)&hlds[row * 128 + ch * 8];
                *(volatile u64x2*)(hd + (size_t)(bbq * 16 + row) * HH + jb * 128 + ch * 8) = v;
            }
            asm volatile("s_waitcnt vmcnt(0)" ::: "memory");
            __syncthreads();                               // (E) all waves' stores in L2
            if (tid == 0)
                __hip_atomic_fetch_add(&cnt2[bbq], 1u, __ATOMIC_RELAXED,
                                       __HIP_MEMORY_SCOPE_WORKGROUP);  // L2-point RMW
        } else {
            if (tid < 64) {
                #pragma unroll
                for (int c = 0; c < 8; ++c) {
                    const int q   = tid + c * 64;
                    const int row = q >> 5, cc = q & 31;
                    u64 v = *(const u64*)&hlds[row * 128 + cc * 4];
                    hstore(hd + (size_t)(bbq * 16 + row) * HH + jb * 128 + cc * 4, v);
                }
                asm volatile("s_waitcnt vmcnt(0)" ::: "memory");
                if (tid == 0)
                    __hip_atomic_fetch_add(&cnt[bbq], 1u, __ATOMIC_RELAXED,
                                           __HIP_MEMORY_SCOPE_AGENT);
            }
        }

        // y finalization off the critical path
        if (tid >= 64 && tid < 80) {
            const int b = tid - 64;
            const float y = y_red[0 * 16 + b] + y_red[1 * 16 + b] +
                            y_red[2 * 16 + b] + y_red[3 * 16 + b] + bout;
            atomicAdd(&out[(size_t)s * BATCH + bbq * 16 + b], y);
        }
    }
}

// Grid: 128 wgs, 256 threads. bbq = wg&15, jb = wg>>4 so the 8 wgs of a
// b-group share blockIdx mod 8 -> same XCD under round-robin dispatch.
// Colocation is VERIFIED at runtime (HW_REG_XCC_ID exchange); only then is
// the L2-local fast path taken, else the MALL fallback. Correct either way.
__global__ __launch_bounds__(256, 1)
void rnn_persistent(const float* __restrict__ x0,
                    const float* __restrict__ hidden0,
                    const float* __restrict__ targets,
                    const float* __restrict__ W_ih,
                    const float* __restrict__ W_hh,
                    const float* __restrict__ b_ih,
                    const float* __restrict__ b_hh,
                    const float* __restrict__ W_out,
                    const float* __restrict__ b_out,
                    float*       __restrict__ out,     // pre-zeroed
                    _Float16*    __restrict__ hbuf0,
                    _Float16*    __restrict__ hbuf1,
                    unsigned*    __restrict__ cnt,     // [16] agent counters
                    unsigned*    __restrict__ cnt2,    // [16] L2-local counters
                    unsigned*    __restrict__ xcds)    // [128] XCC ids
{
    const int wg  = blockIdx.x;
    const int bbq = wg & 15;
    const int jb  = wg >> 4;
    const int tid = threadIdx.x;
    const int w   = tid >> 6;
    const int l   = tid & 63;
    const int l15 = l & 15;
    const int lhi = l >> 4;

    __shared__ __align__(16) float    x_lds[16];
    __shared__ __align__(16) float    red[4 * 8 * 256];
    __shared__ __align__(16) float    y_red[4 * 16];
    __shared__ __align__(16) _Float16 hlds[16 * 128];
    __shared__ __align__(16) _Float16 hstage[16 * 1024];
    __shared__            int         fastflag;

    unsigned xcc;
    asm volatile("s_getreg_b32 %0, hwreg(HW_REG_XCC_ID)" : "=s"(xcc));

    // ---- one-time: W_hh slice (128 cols x 1024 K) -> f16 B-frags in VGPRs ----
    half8 wfrag[8][8];
    {
        const int kbase = w * 256 + lhi * 8;
        #pragma unroll
        for (int jf = 0; jf < 8; ++jf) {
            const float* wr = W_hh + (size_t)(jb * 128 + jf * 16 + l15) * HH + kbase;
            #pragma unroll
            for (int kk = 0; kk < 8; ++kk) {
                floatx4 lo = *(const floatx4*)(wr + kk * 32);
                floatx4 hi = *(const floatx4*)(wr + kk * 32 + 4);
                half8 f;
                f[0]=(_Float16)lo[0]; f[1]=(_Float16)lo[1]; f[2]=(_Float16)lo[2]; f[3]=(_Float16)lo[3];
                f[4]=(_Float16)hi[0]; f[5]=(_Float16)hi[1]; f[6]=(_Float16)hi[2]; f[7]=(_Float16)hi[3];
                wfrag[jf][kk] = f;
            }
        }
    }

    const int   jcol0  = jb * 128 + w * 16 + l15;
    const int   jcol1  = jcol0 + 64;
    const float bias0  = b_ih[jcol0] + b_hh[jcol0];
    const float bias1  = b_ih[jcol1] + b_hh[jcol1];
    const float wih0   = W_ih[jcol0], wih1 = W_ih[jcol1];
    const float wout0  = W_out[jcol0], wout1 = W_out[jcol1];
    const float bout   = (jb == 0) ? b_out[0] : 0.f;

    int lra[8];
    #pragma unroll
    for (int kk = 0; kk < 8; ++kk) {
        const int cb = w * 512 + lhi * 16 + kk * 64;
        lra[kk] = l15 * 2048 + (cb ^ ((l15 & 7) << 4));
    }
    char* hstage_b = (char*)hstage;

    // ---- init: fp32 hidden -> f16 hbuf0 (agent stores) + publish XCC id ----
    #pragma unroll
    for (int c = 0; c < 2; ++c) {
        const int q   = tid + c * 256;
        const int row = q >> 5, cc = q & 31;
        const float* s = hidden0 + (size_t)(bbq * 16 + row) * HH + jb * 128 + cc * 4;
        floatx4 f4 = *(const floatx4*)s;
        half4 h4;
        h4[0]=(_Float16)f4[0]; h4[1]=(_Float16)f4[1]; h4[2]=(_Float16)f4[2]; h4[3]=(_Float16)f4[3];
        hstore(hbuf0 + (size_t)(bbq * 16 + row) * HH + jb * 128 + cc * 4,
               __builtin_bit_cast(u64, h4));
    }
    if (tid == 0)
        __hip_atomic_store(&xcds[wg], xcc, __ATOMIC_RELAXED, __HIP_MEMORY_SCOPE_AGENT);
    asm volatile("s_waitcnt vmcnt(0)" ::: "memory");
    __syncthreads();
    if (tid == 0)
        __hip_atomic_fetch_add(&cnt[bbq], 1u, __ATOMIC_RELAXED, __HIP_MEMORY_SCOPE_AGENT);

    // ---- verdict: are all 8 group members on one XCD? ----
    if (tid == 0) {
        while (__hip_atomic_load(&cnt[bbq], __ATOMIC_RELAXED,
                                 __HIP_MEMORY_SCOPE_AGENT) < 8u) {}
    }
    __syncthreads();
    if (tid < 64) {
        unsigned v = 0;
        if (l < 8)
            v = __hip_atomic_load(&xcds[l * 16 + bbq], __ATOMIC_RELAXED,
                                  __HIP_MEMORY_SCOPE_AGENT);
        const unsigned v0 = __shfl(v, 0);
        const bool ok = (l >= 8) || (v == v0);
        const unsigned long long m = __ballot(ok);
        if (tid == 0) fastflag = (m == ~0ull) ? 1 : 0;
    }
    __syncthreads();
    const bool fast = (fastflag != 0);

    if (fast)
        run_steps<true >(bbq, jb, tid, w, l15, lhi, x0, targets, out,
                         hbuf0, hbuf1, cnt, cnt2, wfrag, lra,
                         bias0, bias1, wih0, wih1, wout0, wout1, bout,
                         x_lds, red, y_red, hlds, hstage_b);
    else
        run_steps<false>(bbq, jb, tid, w, l15, lhi, x0, targets, out,
                         hbuf0, hbuf1, cnt, cnt2, wfrag, lra,
                         bias0, bias1, wih0, wih1, wout0, wout1, bout,
                         x_lds, red, y_red, hlds, hstage_b);
}

extern "C" void kernel_launch(void* const* d_in, const int* in_sizes, int n_in,
                              void* d_out, int out_size, void* d_ws, size_t ws_size,
                              hipStream_t stream)
{
    const float* x0      = (const float*)d_in[0];
    const float* hidden0 = (const float*)d_in[1];
    const float* targets = (const float*)d_in[2];
    const float* W_ih    = (const float*)d_in[3];
    const float* W_hh    = (const float*)d_in[4];
    const float* b_ih    = (const float*)d_in[5];
    const float* b_hh    = (const float*)d_in[6];
    const float* W_out   = (const float*)d_in[7];
    const float* b_out   = (const float*)d_in[8];
    float* out = (float*)d_out;

    char* ws = (char*)d_ws;
    unsigned* cnt   = (unsigned*)ws;                          // [16]  @0
    unsigned* cnt2  = (unsigned*)(ws + 64);                   // [16]  @64
    unsigned* xcds  = (unsigned*)(ws + 128);                  // [128] @128
    _Float16* hbuf0 = (_Float16*)(ws + 1024);                 // 512 KB
    _Float16* hbuf1 = (_Float16*)(ws + 1024 + 512 * 1024);    // 512 KB

    hipMemsetAsync(ws, 0, 1024, stream);
    hipMemsetAsync(d_out, 0, (size_t)out_size * sizeof(float), stream);

    rnn_persistent<<<128, 256, 0, stream>>>(x0, hidden0, targets, W_ih, W_hh,
                                            b_ih, b_hh, W_out, b_out,
                                            out, hbuf0, hbuf1, cnt, cnt2, xcds);
}

// Round 8
// 1948.575 us; speedup vs baseline: 5.4579x; 1.2494x over previous
//
#include <hip/hip_runtime.h>

#define TT 512
#define BATCH 256
#define HH 1024

typedef _Float16 half4  __attribute__((ext_vector_type(4)));
typedef _Float16 half8  __attribute__((ext_vector_type(8)));
typedef float    floatx4 __attribute__((ext_vector_type(4)));
typedef unsigned uint4v  __attribute__((ext_vector_type(4)));
typedef unsigned long long u64;
typedef u64 u64x2 __attribute__((ext_vector_type(2)));

// Agent-scope (MALL-coherent) 8B ops — fallback path + init.
__device__ __forceinline__ u64 hload(const _Float16* p) {
    return __hip_atomic_load((const u64*)p, __ATOMIC_RELAXED, __HIP_MEMORY_SCOPE_AGENT);
}
__device__ __forceinline__ void hstore(_Float16* p, u64 v) {
    __hip_atomic_store((u64*)p, v, __ATOMIC_RELAXED, __HIP_MEMORY_SCOPE_AGENT);
}

// One RNN step-loop.
// FAST (group verified on one XCD): h' published with PLAIN (writeback-L2)
//   stores; release = vmcnt(0) ack (L1 is write-through -> data in L2) then an
//   sc0 per-producer FLAG store. Consumers poll 8 flags (2x dwordx4 volatile)
//   and read h with sc0 loads (L1-bypassed, L2-served). No RMW, no HBM trip.
// !FAST: agent-scope 8B atomics via MALL + agent counter (placement-agnostic).
// Waves are jf-split (each wave: 2 col-blocks x full K) -> no cross-wave
// reduction, 3 barriers/step.
template<bool FAST>
__device__ __forceinline__ void run_steps(
    int bbq, int jb, int tid, int w, int l15, int lhi,
    const float* __restrict__ x0, const float* __restrict__ targets,
    float* __restrict__ out,
    _Float16* __restrict__ hbuf0, _Float16* __restrict__ hbuf1,
    unsigned* __restrict__ cnt, unsigned* __restrict__ flags,
    const half8 (&wfrag)[2][32], int e0, int e1,
    float bias0, float bias1, float wih0, float wih1,
    float wout0, float wout1, float bout,
    float* x_lds, float* y_red, _Float16* hlds, char* hstage_b)
{
    for (int s = 0; s < TT; ++s) {
        const _Float16* hs = (s & 1) ? hbuf1 : hbuf0;
        _Float16*       hd = (s & 1) ? hbuf0 : hbuf1;

        float xval = 0.f;
        if (tid < 16)
            xval = (s == 0) ? x0[bbq * 16 + tid]
                            : targets[(size_t)(s - 1) * BATCH + bbq * 16 + tid];

        // ---- wait for all 8 producers of the previous step ----
        if (tid == 0) {
            if (FAST) {
                const unsigned tgt = (unsigned)s;          // flag==s: step s-1 done
                for (;;) {
                    uint4v a = *(volatile const uint4v*)&flags[bbq * 8];
                    uint4v b = *(volatile const uint4v*)&flags[bbq * 8 + 4];
                    unsigned m = a[0];
                    m = m < a[1] ? m : a[1]; m = m < a[2] ? m : a[2];
                    m = m < a[3] ? m : a[3]; m = m < b[0] ? m : b[0];
                    m = m < b[1] ? m : b[1]; m = m < b[2] ? m : b[2];
                    m = m < b[3] ? m : b[3];
                    if (m >= tgt) break;
                }
            } else {
                const unsigned tgt = 8u * (unsigned)(s + 1); // init + prev steps
                while (__hip_atomic_load(&cnt[bbq], __ATOMIC_RELAXED,
                                         __HIP_MEMORY_SCOPE_AGENT) < tgt) {}
            }
        }
        if (tid < 16) x_lds[tid] = xval;
        __syncthreads();                                   // (A)
        __builtin_amdgcn_sched_barrier(0);

        // ---- stage group h-tile (16 x 1024 f16 = 32 KB) into swizzled LDS ----
        if (FAST) {
            const char* gsrc = (const char*)(hs + (size_t)bbq * 16 * HH);
            u64x2 sv[8];
            #pragma unroll
            for (int i = 0; i < 8; ++i) {
                const int c = tid + i * 256;               // 2048 x 16B chunks
                sv[i] = *(volatile const u64x2*)(gsrc + (c >> 7) * 2048 + (c & 127) * 16);
            }
            __builtin_amdgcn_sched_barrier(0);             // all loads issue first
            #pragma unroll
            for (int i = 0; i < 8; ++i) {
                const int c = tid + i * 256;
                const int row = c >> 7, colb = (c & 127) * 16;
                *(u64x2*)(hstage_b + row * 2048 + (colb ^ ((row & 7) << 4))) = sv[i];
            }
        } else {
            const _Float16* sb = hs + (size_t)bbq * 16 * HH;
            u64 sv[16];
            #pragma unroll
            for (int r = 0; r < 16; ++r)
                sv[r] = hload(sb + r * HH + tid * 4);
            __builtin_amdgcn_sched_barrier(0);
            #pragma unroll
            for (int r = 0; r < 16; ++r)
                *(u64*)(hstage_b + r * 2048 + ((tid * 8) ^ ((r & 7) << 4))) = sv[r];
        }
        __syncthreads();                                   // (B)

        // ---- full-K MFMA: wave w owns col-blocks {w, w+4}; 4 acc chains ----
        floatx4 a00 = {0,0,0,0}, a01 = {0,0,0,0}, a10 = {0,0,0,0}, a11 = {0,0,0,0};
        #pragma unroll
        for (int t = 0; t < 16; ++t) {
            const half8 av0 = *(const half8*)(hstage_b + e0 + t * 128);
            const half8 av1 = *(const half8*)(hstage_b + e1 + t * 128);
            a00 = __builtin_amdgcn_mfma_f32_16x16x32_f16(av0, wfrag[0][2 * t],     a00, 0, 0, 0);
            a10 = __builtin_amdgcn_mfma_f32_16x16x32_f16(av0, wfrag[1][2 * t],     a10, 0, 0, 0);
            a01 = __builtin_amdgcn_mfma_f32_16x16x32_f16(av1, wfrag[0][2 * t + 1], a01, 0, 0, 0);
            a11 = __builtin_amdgcn_mfma_f32_16x16x32_f16(av1, wfrag[1][2 * t + 1], a11, 0, 0, 0);
        }
        const floatx4 xv = *(const floatx4*)&x_lds[lhi * 4];

        float ht0[4], ht1[4];
        #pragma unroll
        for (int r = 0; r < 4; ++r) {
            const float p0 = a00[r] + a01[r] + bias0 + xv[r] * wih0;
            const float p1 = a10[r] + a11[r] + bias1 + xv[r] * wih1;
            const float ex0 = __expf(2.0f * p0);
            const float ex1 = __expf(2.0f * p1);
            ht0[r] = 1.0f - 2.0f / (ex0 + 1.0f);
            ht1[r] = 1.0f - 2.0f / (ex1 + 1.0f);
        }

        // stage h' (f16) for wave-0 publish
        #pragma unroll
        for (int r = 0; r < 4; ++r) {
            hlds[(lhi * 4 + r) * 128 + (w * 16 + l15)]      = (_Float16)ht0[r];
            hlds[(lhi * 4 + r) * 128 + (w * 16 + l15) + 64] = (_Float16)ht1[r];
        }

        // y partials (2 cols/lane), 16-lane shuffle reduce
        float yv[4];
        #pragma unroll
        for (int r = 0; r < 4; ++r) yv[r] = ht0[r] * wout0 + ht1[r] * wout1;
        #pragma unroll
        for (int off = 1; off < 16; off <<= 1) {
            #pragma unroll
            for (int r = 0; r < 4; ++r) yv[r] += __shfl_xor(yv[r], off);
        }
        if (l15 == 0) {
            #pragma unroll
            for (int r = 0; r < 4; ++r) y_red[w * 16 + lhi * 4 + r] = yv[r];
        }
        __syncthreads();                                   // (D)

        // ---- wave 0 publishes h' (4 KB) and signals; others move on ----
        if (tid < 64) {
            if (FAST) {
                #pragma unroll
                for (int c = 0; c < 4; ++c) {
                    const int q   = tid + c * 64;          // 256 x 16B chunks
                    const int row = q >> 4, ch = q & 15;
                    u64x2 v = *(const u64x2*)&hlds[row * 128 + ch * 8];
                    *(u64x2*)(hd + (size_t)(bbq * 16 + row) * HH + jb * 128 + ch * 8) = v;
                }
                asm volatile("s_waitcnt vmcnt(0)" ::: "memory"); // data in L2
                if (tid == 0)
                    *(volatile unsigned*)&flags[bbq * 8 + jb] = (unsigned)(s + 1);
            } else {
                #pragma unroll
                for (int c = 0; c < 8; ++c) {
                    const int q   = tid + c * 64;
                    const int row = q >> 5, cc = q & 31;
                    u64 v = *(const u64*)&hlds[row * 128 + cc * 4];
                    hstore(hd + (size_t)(bbq * 16 + row) * HH + jb * 128 + cc * 4, v);
                }
                asm volatile("s_waitcnt vmcnt(0)" ::: "memory");
                if (tid == 0)
                    __hip_atomic_fetch_add(&cnt[bbq], 1u, __ATOMIC_RELAXED,
                                           __HIP_MEMORY_SCOPE_AGENT);
            }
        }

        // y finalization off the critical path
        if (tid >= 64 && tid < 80) {
            const int b = tid - 64;
            const float y = y_red[0 * 16 + b] + y_red[1 * 16 + b] +
                            y_red[2 * 16 + b] + y_red[3 * 16 + b] + bout;
            atomicAdd(&out[(size_t)s * BATCH + bbq * 16 + b], y);
        }
    }
}

// Grid: 128 wgs, 256 threads. bbq = wg&15, jb = wg>>4 -> the 8 wgs of a
// b-group share blockIdx mod 8 -> same XCD under round-robin dispatch.
// Colocation VERIFIED at runtime (HW_REG_XCC_ID exchange); L2-local fast path
// only when verified, else MALL fallback. Correct either way.
__global__ __launch_bounds__(256, 1)
void rnn_persistent(const float* __restrict__ x0,
                    const float* __restrict__ hidden0,
                    const float* __restrict__ targets,
                    const float* __restrict__ W_ih,
                    const float* __restrict__ W_hh,
                    const float* __restrict__ b_ih,
                    const float* __restrict__ b_hh,
                    const float* __restrict__ W_out,
                    const float* __restrict__ b_out,
                    float*       __restrict__ out,     // pre-zeroed
                    _Float16*    __restrict__ hbuf0,
                    _Float16*    __restrict__ hbuf1,
                    unsigned*    __restrict__ cnt,     // [16] agent counters
                    unsigned*    __restrict__ flags,   // [16][8] step flags
                    unsigned*    __restrict__ xcds)    // [128] XCC ids
{
    const int wg  = blockIdx.x;
    const int bbq = wg & 15;
    const int jb  = wg >> 4;
    const int tid = threadIdx.x;
    const int w   = tid >> 6;
    const int l   = tid & 63;
    const int l15 = l & 15;
    const int lhi = l >> 4;

    __shared__ __align__(16) float    x_lds[16];
    __shared__ __align__(16) float    y_red[4 * 16];
    __shared__ __align__(16) _Float16 hlds[16 * 128];
    __shared__ __align__(16) _Float16 hstage[16 * 1024];
    __shared__            int         fastflag;

    unsigned xcc;
    asm volatile("s_getreg_b32 %0, hwreg(HW_REG_XCC_ID)" : "=s"(xcc));

    const int   jcol0  = jb * 128 + w * 16 + l15;
    const int   jcol1  = jcol0 + 64;

    // ---- one-time: W_hh cols {jcol0, jcol1} full-K -> f16 B-frags (256 VGPR) ----
    half8 wfrag[2][32];
    #pragma unroll
    for (int c = 0; c < 2; ++c) {
        const float* wr = W_hh + (size_t)(c ? jcol1 : jcol0) * HH + lhi * 8;
        #pragma unroll
        for (int kk = 0; kk < 32; ++kk) {
            floatx4 lo = *(const floatx4*)(wr + kk * 32);
            floatx4 hi = *(const floatx4*)(wr + kk * 32 + 4);
            half8 f;
            f[0]=(_Float16)lo[0]; f[1]=(_Float16)lo[1]; f[2]=(_Float16)lo[2]; f[3]=(_Float16)lo[3];
            f[4]=(_Float16)hi[0]; f[5]=(_Float16)hi[1]; f[6]=(_Float16)hi[2]; f[7]=(_Float16)hi[3];
            wfrag[c][kk] = f;
        }
    }

    const float bias0  = b_ih[jcol0] + b_hh[jcol0];
    const float bias1  = b_ih[jcol1] + b_hh[jcol1];
    const float wih0   = W_ih[jcol0], wih1 = W_ih[jcol1];
    const float wout0  = W_out[jcol0], wout1 = W_out[jcol1];
    const float bout   = (jb == 0) ? b_out[0] : 0.f;

    // swizzled LDS byte-addrs for the A-frag reads: addr = e{u} + (kk>>1)*128
    const int xm = (l15 & 7) << 4;
    const int e0 = l15 * 2048 + ((lhi * 16) ^ xm);
    const int e1 = l15 * 2048 + ((64 + lhi * 16) ^ xm);
    char* hstage_b = (char*)hstage;

    // ---- init: fp32 hidden -> f16 hbuf0 (agent stores) + publish XCC id ----
    #pragma unroll
    for (int c = 0; c < 2; ++c) {
        const int q   = tid + c * 256;
        const int row = q >> 5, cc = q & 31;
        const float* s = hidden0 + (size_t)(bbq * 16 + row) * HH + jb * 128 + cc * 4;
        floatx4 f4 = *(const floatx4*)s;
        half4 h4;
        h4[0]=(_Float16)f4[0]; h4[1]=(_Float16)f4[1]; h4[2]=(_Float16)f4[2]; h4[3]=(_Float16)f4[3];
        hstore(hbuf0 + (size_t)(bbq * 16 + row) * HH + jb * 128 + cc * 4,
               __builtin_bit_cast(u64, h4));
    }
    if (tid == 0)
        __hip_atomic_store(&xcds[wg], xcc, __ATOMIC_RELAXED, __HIP_MEMORY_SCOPE_AGENT);
    asm volatile("s_waitcnt vmcnt(0)" ::: "memory");
    __syncthreads();
    if (tid == 0)
        __hip_atomic_fetch_add(&cnt[bbq], 1u, __ATOMIC_RELAXED, __HIP_MEMORY_SCOPE_AGENT);

    // ---- verdict: all 8 group members on one XCD? ----
    if (tid == 0) {
        while (__hip_atomic_load(&cnt[bbq], __ATOMIC_RELAXED,
                                 __HIP_MEMORY_SCOPE_AGENT) < 8u) {}
    }
    __syncthreads();
    if (tid < 64) {
        unsigned v = 0;
        if (l < 8)
            v = __hip_atomic_load(&xcds[(l << 4) + bbq], __ATOMIC_RELAXED,
                                  __HIP_MEMORY_SCOPE_AGENT);
        const unsigned v0 = __shfl(v, 0);
        const bool ok = (l >= 8) || (v == v0);
        const unsigned long long m = __ballot(ok);
        if (tid == 0) fastflag = (m == ~0ull) ? 1 : 0;
    }
    __syncthreads();
    const bool fast = (fastflag != 0);

    if (fast)
        run_steps<true >(bbq, jb, tid, w, l15, lhi, x0, targets, out,
                         hbuf0, hbuf1, cnt, flags, wfrag, e0, e1,
                         bias0, bias1, wih0, wih1, wout0, wout1, bout,
                         x_lds, y_red, hlds, hstage_b);
    else
        run_steps<false>(bbq, jb, tid, w, l15, lhi, x0, targets, out,
                         hbuf0, hbuf1, cnt, flags, wfrag, e0, e1,
                         bias0, bias1, wih0, wih1, wout0, wout1, bout,
                         x_lds, y_red, hlds, hstage_b);
}

extern "C" void kernel_launch(void* const* d_in, const int* in_sizes, int n_in,
                              void* d_out, int out_size, void* d_ws, size_t ws_size,
                              hipStream_t stream)
{
    const float* x0      = (const float*)d_in[0];
    const float* hidden0 = (const float*)d_in[1];
    const float* targets = (const float*)d_in[2];
    const float* W_ih    = (const float*)d_in[3];
    const float* W_hh    = (const float*)d_in[4];
    const float* b_ih    = (const float*)d_in[5];
    const float* b_hh    = (const float*)d_in[6];
    const float* W_out   = (const float*)d_in[7];
    const float* b_out   = (const float*)d_in[8];
    float* out = (float*)d_out;

    char* ws = (char*)d_ws;
    unsigned* cnt   = (unsigned*)ws;                          // [16]     @0
    unsigned* flags = (unsigned*)(ws + 256);                  // [16][8]  @256
    unsigned* xcds  = (unsigned*)(ws + 1024);                 // [128]    @1024
    _Float16* hbuf0 = (_Float16*)(ws + 4096);                 // 512 KB
    _Float16* hbuf1 = (_Float16*)(ws + 4096 + 512 * 1024);    // 512 KB

    hipMemsetAsync(ws, 0, 4096, stream);
    hipMemsetAsync(d_out, 0, (size_t)out_size * sizeof(float), stream);

    rnn_persistent<<<128, 256, 0, stream>>>(x0, hidden0, targets, W_ih, W_hh,
                                            b_ih, b_hh, W_out, b_out,
                                            out, hbuf0, hbuf1, cnt, flags, xcds);
}